// Round 1
// baseline (1538.661 us; speedup 1.0000x reference)
//
#include <hip/hip_runtime.h>
#include <hip/hip_bf16.h>
#include <cstdint>
#include <cstddef>

typedef __bf16 bf16_t;
typedef __bf16 bf16x8 __attribute__((ext_vector_type(8)));
typedef __bf16 bf16x4 __attribute__((ext_vector_type(4)));
typedef float f32x4 __attribute__((ext_vector_type(4)));

static constexpr int LD = 29 * 128;  // 3712: row stride of x and out (floats)

// ---------------- weight prep ----------------

__global__ void cvt_w0_kernel(const float* __restrict__ in, bf16_t* __restrict__ out, int n) {
    int i = blockIdx.x * 256 + threadIdx.x;
    if (i < n) out[i] = (bf16_t)in[i];
}

// Build combined weight Wc (2*of x 2*din) from W (2*of x din):
//   rows [0,of):    Wc[j]      = [ W[j,:],    -W[j+of,:] ]   (pos outputs)
//   rows [of,2of):  Wc[of + j] = [ W[j+of,:],  W[j,:]    ]   (neg outputs)
__global__ void combine_wm_kernel(const float* __restrict__ W, bf16_t* __restrict__ Wc,
                                  int of, int din, int total) {
    int idx = blockIdx.x * 256 + threadIdx.x;
    if (idx >= total) return;
    int twodin = 2 * din;
    int r = idx / twodin;
    int c = idx - r * twodin;
    float v;
    if (r < of) {
        v = (c < din) ? W[(size_t)r * din + c]
                      : -W[(size_t)(r + of) * din + (c - din)];
    } else {
        int j = r - of;
        v = (c < din) ? W[(size_t)(j + of) * din + c]
                      : W[(size_t)j * din + (c - din)];
    }
    Wc[idx] = (bf16_t)v;
}

// ---------------- GEMM: Y[m, n] = sum_k X[m,k] * W[n,k] (+ bias[n]) ----------------
// X: f32, row stride LD. W: bf16 row-major (N x K). Y: f32, row stride LD.
// 128x128 tile, BK=32, 256 threads = 4 waves in 2x2, each wave 64x64 via 4x4
// mfma_f32_16x16x32_bf16 fragments.

template <int N, int K, bool BIAS>
__global__ __launch_bounds__(256, 2)
void gemm_kernel(const float* __restrict__ X, const bf16_t* __restrict__ W,
                 const float* __restrict__ bias, float* __restrict__ Y, int M) {
    constexpr int BM = 128, BK = 32;
    constexpr int KT = K / BK;

    __shared__ bf16_t As[BM][BK + 8];  // padded: stride 40 el = 80 B -> 2-way banks (free)
    __shared__ bf16_t Bs[BM][BK];      // linear (global_load_lds dest), content chunk-swizzled

    const int tid  = threadIdx.x;
    const int wid  = tid >> 6;
    const int lane = tid & 63;
    const int wr   = wid >> 1;  // wave row (0..1)
    const int wc   = wid & 1;   // wave col (0..1)

    const int m0 = blockIdx.y * BM;
    const int n0 = blockIdx.x * 128;

    // A staging: per pass p, 32 rows; 8 threads/row, float4 each
    const int ar = tid >> 3;        // 0..31
    const int ac = (tid & 7) * 4;   // 0,4,...,28

    // B staging via global_load_lds: wave covers 16 rows/issue, lane -> (row, 16B chunk)
    const int brow0  = wid * 16 + (lane >> 2);
    const int bchunk = lane & 3;

    const int lrow = lane & 15;  // fragment row (A) / col (B,D)
    const int koff = lane >> 4;  // k-chunk 0..3 (8 bf16 each)

    f32x4 acc[4][4] = {};

    for (int kt = 0; kt < KT; ++kt) {
        const int k0 = kt * BK;

        // ---- stage B (2 x 1KB per wave), source pre-swizzled so LDS holds
        //      chunk c = original chunk (c ^ ((row>>1)&3))
        #pragma unroll
        for (int s = 0; s < 2; ++s) {
            const int row = brow0 + s * 64;
            const int kc  = bchunk ^ ((row >> 1) & 3);
            const bf16_t* gsrc = W + (size_t)(n0 + row) * K + k0 + kc * 8;
            bf16_t* ldsbase = &Bs[wid * 16 + s * 64][0];  // wave-uniform
            __builtin_amdgcn_global_load_lds(
                (const __attribute__((address_space(1))) void*)gsrc,
                (__attribute__((address_space(3))) void*)ldsbase, 16, 0, 0);
        }

        // ---- stage A: f32 -> bf16 cvt, reg -> LDS
        #pragma unroll
        for (int p = 0; p < 4; ++p) {
            const int row = p * 32 + ar;
            const int gr  = m0 + row;
            f32x4 v = {};
            if (gr < M) v = *(const f32x4*)(X + (size_t)gr * LD + k0 + ac);
            bf16x4 h;
            h[0] = (bf16_t)v[0]; h[1] = (bf16_t)v[1];
            h[2] = (bf16_t)v[2]; h[3] = (bf16_t)v[3];
            *(bf16x4*)(&As[row][ac]) = h;
        }

        __syncthreads();

        // ---- fragments + MFMA
        bf16x8 a[4], b[4];
        #pragma unroll
        for (int i = 0; i < 4; ++i) {
            a[i] = *(const bf16x8*)(&As[wr * 64 + i * 16 + lrow][koff * 8]);
            const int col = wc * 64 + i * 16 + lrow;
            const int kc  = koff ^ ((col >> 1) & 3);
            b[i] = *(const bf16x8*)(&Bs[col][kc * 8]);
        }
        #pragma unroll
        for (int i = 0; i < 4; ++i)
            #pragma unroll
            for (int j = 0; j < 4; ++j)
                acc[i][j] = __builtin_amdgcn_mfma_f32_16x16x32_bf16(a[i], b[j], acc[i][j], 0, 0, 0);

        __syncthreads();
    }

    // ---- epilogue: C/D layout col = lane&15, row = (lane>>4)*4 + reg
    #pragma unroll
    for (int j = 0; j < 4; ++j) {
        const int col = n0 + wc * 64 + j * 16 + lrow;
        float bv = 0.f;
        if constexpr (BIAS) bv = bias[col];
        #pragma unroll
        for (int i = 0; i < 4; ++i) {
            const int rbase = m0 + wr * 64 + i * 16 + koff * 4;
            #pragma unroll
            for (int r = 0; r < 4; ++r) {
                const int gr = rbase + r;
                if (gr < M) Y[(size_t)gr * LD + col] = acc[i][j][r] + bv;
            }
        }
    }
}

// ---------------- launch ----------------

extern "C" void kernel_launch(void* const* d_in, const int* in_sizes, int n_in,
                              void* d_out, int out_size, void* d_ws, size_t ws_size,
                              hipStream_t stream) {
    const float* x  = (const float*)d_in[0];
    const float* W0 = (const float*)d_in[1];
    const float* b0 = (const float*)d_in[2];
    const float* W1 = (const float*)d_in[3];
    const float* W2 = (const float*)d_in[4];
    float* out = (float*)d_out;

    const int E = in_sizes[0] / LD;  // 50000

    bf16_t* wc0 = (bf16_t*)d_ws;                 // 896*896
    bf16_t* wc1 = wc0 + 896 * 896;               // 1536*1536
    bf16_t* wc2 = wc1 + 1536 * 1536;             // 1280*1280

    cvt_w0_kernel<<<(896 * 896) / 256, 256, 0, stream>>>(W0, wc0, 896 * 896);
    combine_wm_kernel<<<(1536 * 1536) / 256, 256, 0, stream>>>(W1, wc1, 768, 768, 1536 * 1536);
    combine_wm_kernel<<<(1280 * 1280) / 256, 256, 0, stream>>>(W2, wc2, 640, 640, 1280 * 1280);

    const int mtiles = (E + 127) / 128;
    gemm_kernel<896, 896, true>
        <<<dim3(896 / 128, mtiles), 256, 0, stream>>>(x, wc0, b0, out, E);
    gemm_kernel<1536, 1536, false>
        <<<dim3(1536 / 128, mtiles), 256, 0, stream>>>(x + 896, wc1, nullptr, out + 896, E);
    gemm_kernel<1280, 1280, false>
        <<<dim3(1280 / 128, mtiles), 256, 0, stream>>>(x + 2432, wc2, nullptr, out + 2432, E);
}

// Round 2
// 1092.429 us; speedup vs baseline: 1.4085x; 1.4085x over previous
//
#include <hip/hip_runtime.h>
#include <hip/hip_bf16.h>
#include <cstdint>
#include <cstddef>

typedef __bf16 bf16_t;
typedef __bf16 bf16x8 __attribute__((ext_vector_type(8)));
typedef __bf16 bf16x4 __attribute__((ext_vector_type(4)));
typedef float f32x4 __attribute__((ext_vector_type(4)));

static constexpr int LD = 29 * 128;  // 3712: row stride of x and out (floats)

// ---------------- prep kernels ----------------

__global__ void cvt_w0_kernel(const float* __restrict__ in, bf16_t* __restrict__ out, int n) {
    int i = blockIdx.x * 256 + threadIdx.x;
    if (i < n) out[i] = (bf16_t)in[i];
}

// Build combined weight Wc (2*of x 2*din) from W (2*of x din):
//   rows [0,of):    Wc[j]      = [ W[j,:],    -W[j+of,:] ]   (pos outputs)
//   rows [of,2of):  Wc[of + j] = [ W[j+of,:],  W[j,:]    ]   (neg outputs)
__global__ void combine_wm_kernel(const float* __restrict__ W, bf16_t* __restrict__ Wc,
                                  int of, int din, int total) {
    int idx = blockIdx.x * 256 + threadIdx.x;
    if (idx >= total) return;
    int twodin = 2 * din;
    int r = idx / twodin;
    int c = idx - r * twodin;
    float v;
    if (r < of) {
        v = (c < din) ? W[(size_t)r * din + c]
                      : -W[(size_t)(r + of) * din + (c - din)];
    } else {
        int j = r - of;
        v = (c < din) ? W[(size_t)(j + of) * din + c]
                      : W[(size_t)j * din + (c - din)];
    }
    Wc[idx] = (bf16_t)v;
}

// Whole-x f32 -> bf16 conversion (one pass), 8 elements/thread.
__global__ void cvt_x_kernel(const float* __restrict__ in, bf16_t* __restrict__ out, long n8) {
    long stride = (long)gridDim.x * 256;
    for (long i = blockIdx.x * 256L + threadIdx.x; i < n8; i += stride) {
        f32x4 v0 = *(const f32x4*)(in + i * 8);
        f32x4 v1 = *(const f32x4*)(in + i * 8 + 4);
        bf16x8 h;
        h[0] = (bf16_t)v0[0]; h[1] = (bf16_t)v0[1];
        h[2] = (bf16_t)v0[2]; h[3] = (bf16_t)v0[3];
        h[4] = (bf16_t)v1[0]; h[5] = (bf16_t)v1[1];
        h[6] = (bf16_t)v1[2]; h[7] = (bf16_t)v1[3];
        *(bf16x8*)(out + i * 8) = h;
    }
}

// ---------------- GEMM: Y[m, n] = sum_k Xb[m,k] * W[n,k] (+ bias[n]) ----------------
// Fast path (XBF16): Xb bf16 (row stride LD), both operands via global_load_lds
// width 16 into LINEAR LDS with chunk-XOR pre-swizzled global source
// (kc = c ^ ((row>>1)&3)) -> ds_read_b128 lands 2-way (free).
// Fallback (!XBF16): X f32 reg-staged + cvt (round-1 path).

template <int N, int K, bool BIAS, bool XBF16>
__global__ __launch_bounds__(256)
void gemm_kernel(const float* __restrict__ X, const bf16_t* __restrict__ Xb,
                 const bf16_t* __restrict__ W,
                 const float* __restrict__ bias, float* __restrict__ Y, int M) {
    constexpr int BM = 128, BK = 32;
    constexpr int KT = K / BK;
    constexpr int APAD = XBF16 ? 0 : 8;

    __shared__ bf16_t As[BM][BK + APAD];
    __shared__ bf16_t Bs[BM][BK];

    const int tid  = threadIdx.x;
    const int wid  = tid >> 6;
    const int lane = tid & 63;
    const int wr   = wid >> 1;  // wave row (0..1)
    const int wc   = wid & 1;   // wave col (0..1)

    const int m0 = blockIdx.y * BM;
    const int n0 = blockIdx.x * 128;

    // gl_lds staging: per issue, 64 lanes x 16B = 16 rows x 64B; lane -> (row, chunk)
    const int srow0  = wid * 16 + (lane >> 2);
    const int schunk = lane & 3;

    // fallback A staging
    const int ar = tid >> 3;        // 0..31
    const int ac = (tid & 7) * 4;   // 0,4,...,28

    const int lrow = lane & 15;  // fragment row (A) / col (B,D)
    const int koff = lane >> 4;  // k-chunk 0..3 (8 bf16 each)

    f32x4 acc[4][4] = {};

    for (int kt = 0; kt < KT; ++kt) {
        const int k0 = kt * BK;

        // ---- stage B (global_load_lds, pre-swizzled source)
        #pragma unroll
        for (int s = 0; s < 2; ++s) {
            const int row = srow0 + s * 64;
            const int kc  = schunk ^ ((row >> 1) & 3);
            const bf16_t* gsrc = W + (size_t)(n0 + row) * K + k0 + kc * 8;
            bf16_t* ldsbase = &Bs[wid * 16 + s * 64][0];  // wave-uniform
            __builtin_amdgcn_global_load_lds(
                (const __attribute__((address_space(1))) void*)gsrc,
                (__attribute__((address_space(3))) void*)ldsbase, 16, 0, 0);
        }

        if constexpr (XBF16) {
            // ---- stage A (global_load_lds, pre-swizzled source, row-clamped)
            #pragma unroll
            for (int s = 0; s < 2; ++s) {
                const int row = srow0 + s * 64;
                const int kc  = schunk ^ ((row >> 1) & 3);
                int grow = m0 + row;
                if (grow >= M) grow = M - 1;  // duplicate last row; outputs guarded
                const bf16_t* gsrc = Xb + (size_t)grow * LD + k0 + kc * 8;
                bf16_t* ldsbase = &As[wid * 16 + s * 64][0];  // wave-uniform
                __builtin_amdgcn_global_load_lds(
                    (const __attribute__((address_space(1))) void*)gsrc,
                    (__attribute__((address_space(3))) void*)ldsbase, 16, 0, 0);
            }
        } else {
            // ---- fallback: f32 -> bf16 cvt, reg -> LDS
            #pragma unroll
            for (int p = 0; p < 4; ++p) {
                const int row = p * 32 + ar;
                const int gr  = m0 + row;
                f32x4 v = {};
                if (gr < M) v = *(const f32x4*)(X + (size_t)gr * LD + k0 + ac);
                bf16x4 h;
                h[0] = (bf16_t)v[0]; h[1] = (bf16_t)v[1];
                h[2] = (bf16_t)v[2]; h[3] = (bf16_t)v[3];
                *(bf16x4*)(&As[row][ac]) = h;
            }
        }

        __syncthreads();

        // ---- fragments + MFMA
        bf16x8 a[4], b[4];
        #pragma unroll
        for (int i = 0; i < 4; ++i) {
            const int arow = wr * 64 + i * 16 + lrow;
            if constexpr (XBF16) {
                const int akc = koff ^ ((arow >> 1) & 3);
                a[i] = *(const bf16x8*)(&As[arow][akc * 8]);
            } else {
                a[i] = *(const bf16x8*)(&As[arow][koff * 8]);
            }
            const int col = wc * 64 + i * 16 + lrow;
            const int kc  = koff ^ ((col >> 1) & 3);
            b[i] = *(const bf16x8*)(&Bs[col][kc * 8]);
        }
        #pragma unroll
        for (int i = 0; i < 4; ++i)
            #pragma unroll
            for (int j = 0; j < 4; ++j)
                acc[i][j] = __builtin_amdgcn_mfma_f32_16x16x32_bf16(a[i], b[j], acc[i][j], 0, 0, 0);

        __syncthreads();
    }

    // ---- epilogue: C/D layout col = lane&15, row = (lane>>4)*4 + reg
    #pragma unroll
    for (int j = 0; j < 4; ++j) {
        const int col = n0 + wc * 64 + j * 16 + lrow;
        float bv = 0.f;
        if constexpr (BIAS) bv = bias[col];
        #pragma unroll
        for (int i = 0; i < 4; ++i) {
            const int rbase = m0 + wr * 64 + i * 16 + koff * 4;
            #pragma unroll
            for (int r = 0; r < 4; ++r) {
                const int gr = rbase + r;
                if (gr < M) Y[(size_t)gr * LD + col] = acc[i][j][r] + bv;
            }
        }
    }
}

// ---------------- launch ----------------

extern "C" void kernel_launch(void* const* d_in, const int* in_sizes, int n_in,
                              void* d_out, int out_size, void* d_ws, size_t ws_size,
                              hipStream_t stream) {
    const float* x  = (const float*)d_in[0];
    const float* W0 = (const float*)d_in[1];
    const float* b0 = (const float*)d_in[2];
    const float* W1 = (const float*)d_in[3];
    const float* W2 = (const float*)d_in[4];
    float* out = (float*)d_out;

    const int E = in_sizes[0] / LD;  // 50000

    constexpr size_t W_ELEMS = 896 * 896 + 1536 * 1536 + 1280 * 1280;
    bf16_t* wc0 = (bf16_t*)d_ws;
    bf16_t* wc1 = wc0 + 896 * 896;
    bf16_t* wc2 = wc1 + 1536 * 1536;
    bf16_t* xb  = wc0 + W_ELEMS;

    const size_t need = (W_ELEMS + (size_t)E * LD) * sizeof(bf16_t);
    const bool fast = ws_size >= need;

    cvt_w0_kernel<<<(896 * 896) / 256, 256, 0, stream>>>(W0, wc0, 896 * 896);
    combine_wm_kernel<<<(1536 * 1536) / 256, 256, 0, stream>>>(W1, wc1, 768, 768, 1536 * 1536);
    combine_wm_kernel<<<(1280 * 1280) / 256, 256, 0, stream>>>(W2, wc2, 640, 640, 1280 * 1280);

    const int mtiles = (E + 127) / 128;

    if (fast) {
        const long n8 = (long)E * LD / 8;
        cvt_x_kernel<<<4096, 256, 0, stream>>>(x, xb, n8);
        gemm_kernel<896, 896, true, true>
            <<<dim3(896 / 128, mtiles), 256, 0, stream>>>(nullptr, xb, wc0, b0, out, E);
        gemm_kernel<1536, 1536, false, true>
            <<<dim3(1536 / 128, mtiles), 256, 0, stream>>>(nullptr, xb + 896, wc1, nullptr, out + 896, E);
        gemm_kernel<1280, 1280, false, true>
            <<<dim3(1280 / 128, mtiles), 256, 0, stream>>>(nullptr, xb + 2432, wc2, nullptr, out + 2432, E);
    } else {
        gemm_kernel<896, 896, true, false>
            <<<dim3(896 / 128, mtiles), 256, 0, stream>>>(x, nullptr, wc0, b0, out, E);
        gemm_kernel<1536, 1536, false, false>
            <<<dim3(1536 / 128, mtiles), 256, 0, stream>>>(x + 896, nullptr, wc1, nullptr, out + 896, E);
        gemm_kernel<1280, 1280, false, false>
            <<<dim3(1280 / 128, mtiles), 256, 0, stream>>>(x + 2432, nullptr, wc2, nullptr, out + 2432, E);
    }
}

// Round 3
// 863.984 us; speedup vs baseline: 1.7809x; 1.2644x over previous
//
#include <hip/hip_runtime.h>
#include <hip/hip_bf16.h>
#include <cstdint>
#include <cstddef>

typedef __bf16 bf16_t;
typedef __bf16 bf16x8 __attribute__((ext_vector_type(8)));
typedef __bf16 bf16x4 __attribute__((ext_vector_type(4)));
typedef float f32x4 __attribute__((ext_vector_type(4)));

static constexpr int LD = 29 * 128;  // 3712 floats per row of x / out

// ---------------- prep kernels ----------------

// W0 (896x896) -> bf16, zero-padded to 1024 rows.
__global__ void cvt_w0_pad_kernel(const float* __restrict__ in, bf16_t* __restrict__ out,
                                  int rows_real, int kdim, int total) {
    int idx = blockIdx.x * 256 + threadIdx.x;
    if (idx >= total) return;
    int r = idx / kdim;
    int c = idx - r * kdim;
    out[idx] = (bf16_t)((r < rows_real) ? in[(size_t)r * kdim + c] : 0.f);
}

// Build combined weight Wc (2*of x 2*din) from W (2*of x din):
//   rows [0,of):    Wc[j]      = [ W[j,:],    -W[j+of,:] ]   (pos outputs)
//   rows [of,2of):  Wc[of + j] = [ W[j+of,:],  W[j,:]    ]   (neg outputs)
__global__ void combine_wm_kernel(const float* __restrict__ W, bf16_t* __restrict__ Wc,
                                  int of, int din, int total) {
    int idx = blockIdx.x * 256 + threadIdx.x;
    if (idx >= total) return;
    int twodin = 2 * din;
    int r = idx / twodin;
    int c = idx - r * twodin;
    float v;
    if (r < of) {
        v = (c < din) ? W[(size_t)r * din + c]
                      : -W[(size_t)(r + of) * din + (c - din)];
    } else {
        int j = r - of;
        v = (c < din) ? W[(size_t)(j + of) * din + c]
                      : W[(size_t)j * din + (c - din)];
    }
    Wc[idx] = (bf16_t)v;
}

// Whole-x f32 -> bf16, 8 elems/thread.
__global__ void cvt_x_kernel(const float* __restrict__ in, bf16_t* __restrict__ out, long n8) {
    long stride = (long)gridDim.x * 256;
    for (long i = blockIdx.x * 256L + threadIdx.x; i < n8; i += stride) {
        f32x4 v0 = *(const f32x4*)(in + i * 8);
        f32x4 v1 = *(const f32x4*)(in + i * 8 + 4);
        bf16x8 h;
        h[0] = (bf16_t)v0[0]; h[1] = (bf16_t)v0[1];
        h[2] = (bf16_t)v0[2]; h[3] = (bf16_t)v0[3];
        h[4] = (bf16_t)v1[0]; h[5] = (bf16_t)v1[1];
        h[6] = (bf16_t)v1[2]; h[7] = (bf16_t)v1[3];
        *(bf16x8*)(out + i * 8) = h;
    }
}

// ---------------- 256x256 8-phase GEMM ----------------
// Y[m,n] = sum_k Xb[m,k] * W[n,k] (+bias). Xb bf16 row-stride LD; W bf16 [NPAD][K].
// 512 thr = 8 waves. Per phase: block computes one 128x128 C-quadrant over K=64.
// Wave (awr=wid&3, bwc=wid>>2) owns 32x64 of each quadrant -> 2x4 frags x 2 mfma.
// LDS: 2 buf x {A,B} x 2 halves x [128][64] bf16 = 128 KB, linear dest for
// global_load_lds; involutive chunk swizzle kc = c ^ (row&7) on source & read.
// Schedule per K-tile (buf bu): Q(0,0) -> Q(1,0) -> Q(1,1) -> Q(0,1); stages of
// tile+2 at phases 2 (A0,B0), 3 (A1), 4 (B1); vmcnt(8) at phases 4 & 8
// (vmcnt(0) in last iteration, stages skipped).

#define MMA_Q(QM, QN, AF)                                                            \
    do {                                                                             \
        __builtin_amdgcn_s_setprio(1);                                               \
        _Pragma("unroll") for (int i_ = 0; i_ < 2; ++i_)                             \
        _Pragma("unroll") for (int j_ = 0; j_ < 4; ++j_)                             \
        _Pragma("unroll") for (int kk_ = 0; kk_ < 2; ++kk_)                          \
            acc[QM][QN][i_][j_] = __builtin_amdgcn_mfma_f32_16x16x32_bf16(           \
                AF[i_][kk_], b[j_][kk_], acc[QM][QN][i_][j_], 0, 0, 0);              \
        __builtin_amdgcn_s_setprio(0);                                               \
    } while (0)

#define BAR() __builtin_amdgcn_s_barrier()
#define LGKM0()                                                   \
    do {                                                          \
        asm volatile("s_waitcnt lgkmcnt(0)" ::: "memory");        \
        __builtin_amdgcn_sched_barrier(0);                        \
    } while (0)

template <int NPAD, int K, int NREAL, bool BIAS>
__global__ __launch_bounds__(512, 2)
void gemm256_kernel(const bf16_t* __restrict__ Xb, const bf16_t* __restrict__ W,
                    const float* __restrict__ bias, float* __restrict__ Y, int M) {
    constexpr int NT  = K / 64;   // K-tiles (even for all our shapes)
    constexpr int NIT = NT / 2;
    static_assert(NT % 2 == 0, "NT must be even");

    __shared__ bf16_t lds[2][2][2][128][64];  // [buf][op A/B][half][row][k]

    const int tid  = threadIdx.x;
    const int wid  = tid >> 6;
    const int lane = tid & 63;
    const int awr  = wid & 3;    // wave row-block in quadrant (0..3) -> 32 rows
    const int bwc  = wid >> 2;   // wave col-block in quadrant (0..1) -> 64 cols
    const int lrow = lane & 15;
    const int koff = lane >> 4;

    const long m0 = (long)blockIdx.y * 256;
    const long n0 = (long)blockIdx.x * 256;

    const int sr = tid >> 3;   // staging row within 64-row issue
    const int sc = tid & 7;    // staging 16B chunk

    auto stage_half = [&](int bu, int op, int half, int kt) {
        #pragma unroll
        for (int s = 0; s < 2; ++s) {
            const int r  = s * 64 + sr;
            const int kc = sc ^ (r & 7);
            long grow = (op ? n0 : m0) + half * 128 + r;
            if (!op && grow >= M) grow = M - 1;  // clamp; outputs guarded
            const bf16_t* gsrc = (op ? W : Xb) + grow * (op ? (long)K : (long)LD) + kt * 64 + kc * 8;
            bf16_t* dst = &lds[bu][op][half][0][0] + s * 4096 + wid * 512;
            __builtin_amdgcn_global_load_lds(
                (const __attribute__((address_space(1))) void*)gsrc,
                (__attribute__((address_space(3))) void*)dst, 16, 0, 0);
        }
    };

    bf16x8 a0[2][2], a1[2][2], b[4][2];
    f32x4 acc[2][2][2][4] = {};

    auto load_a = [&](bf16x8 (&a)[2][2], int bu, int half) {
        #pragma unroll
        for (int i = 0; i < 2; ++i)
            #pragma unroll
            for (int kk = 0; kk < 2; ++kk) {
                const int rr = awr * 32 + i * 16 + lrow;
                const int sw = (kk * 4 + koff) ^ (rr & 7);
                a[i][kk] = *(const bf16x8*)(&lds[bu][0][half][rr][sw * 8]);
            }
    };
    auto load_b = [&](int bu, int half) {
        #pragma unroll
        for (int j = 0; j < 4; ++j)
            #pragma unroll
            for (int kk = 0; kk < 2; ++kk) {
                const int rr = bwc * 64 + j * 16 + lrow;
                const int sw = (kk * 4 + koff) ^ (rr & 7);
                b[j][kk] = *(const bf16x8*)(&lds[bu][1][half][rr][sw * 8]);
            }
    };

    auto half_iter = [&](int bu, int ts, bool do_stage, bool lastvm) {
        // P1: Q(0,0)
        load_a(a0, bu, 0);
        load_b(bu, 0);
        BAR(); LGKM0();
        MMA_Q(0, 0, a0);
        BAR();
        // P2: Q(1,0); stage A0,B0 <- tile ts
        load_a(a1, bu, 1);
        if (do_stage) { stage_half(bu, 0, 0, ts); stage_half(bu, 1, 0, ts); }
        BAR(); LGKM0();
        MMA_Q(1, 0, a1);
        BAR();
        // P3: Q(1,1); stage A1
        load_b(bu, 1);
        if (do_stage) stage_half(bu, 0, 1, ts);
        BAR(); LGKM0();
        MMA_Q(1, 1, a1);
        BAR();
        // P4: Q(0,1); stage B1; counted vmcnt
        if (do_stage) stage_half(bu, 1, 1, ts);
        if (lastvm) asm volatile("s_waitcnt vmcnt(0)" ::: "memory");
        else        asm volatile("s_waitcnt vmcnt(8)" ::: "memory");
        BAR(); LGKM0();
        MMA_Q(0, 1, a0);
        BAR();
    };

    // prologue: tiles 0 (buf0) and 1 (buf1); drain so tile0 is landed
    #pragma unroll
    for (int h = 0; h < 2; ++h) { stage_half(0, 0, h, 0); stage_half(0, 1, h, 0); }
    #pragma unroll
    for (int h = 0; h < 2; ++h) { stage_half(1, 0, h, 1); stage_half(1, 1, h, 1); }
    asm volatile("s_waitcnt vmcnt(8)" ::: "memory");
    BAR();

    #pragma unroll 1
    for (int it = 0; it < NIT; ++it) {
        const bool st = (it < NIT - 1);
        const bool lv = (it == NIT - 1);
        half_iter(0, 2 * it + 2, st, lv);
        half_iter(1, 2 * it + 3, st, lv);
    }

    // epilogue: C/D layout col = lane&15, row = (lane>>4)*4 + reg
    #pragma unroll
    for (int qm = 0; qm < 2; ++qm)
        #pragma unroll
        for (int qn = 0; qn < 2; ++qn)
            #pragma unroll
            for (int j = 0; j < 4; ++j) {
                const long col = n0 + qn * 128 + bwc * 64 + j * 16 + lrow;
                if (col < NREAL) {
                    float bv = 0.f;
                    if constexpr (BIAS) bv = bias[col];
                    #pragma unroll
                    for (int i = 0; i < 2; ++i) {
                        const long rbase = m0 + qm * 128 + awr * 32 + i * 16 + koff * 4;
                        #pragma unroll
                        for (int r = 0; r < 4; ++r) {
                            const long row = rbase + r;
                            if (row < M) Y[row * LD + col] = acc[qm][qn][i][j][r] + bv;
                        }
                    }
                }
            }
}

// ---------------- fallback 128^2 GEMM (f32 x, reg-staged) ----------------

template <int N, int K, bool BIAS>
__global__ __launch_bounds__(256)
void gemm_fb_kernel(const float* __restrict__ X, const bf16_t* __restrict__ W,
                    const float* __restrict__ bias, float* __restrict__ Y, int M) {
    constexpr int BM = 128, BK = 32;
    constexpr int KT = K / BK;
    __shared__ bf16_t As[BM][BK + 8];
    __shared__ bf16_t Bs[BM][BK];
    const int tid = threadIdx.x, wid = tid >> 6, lane = tid & 63;
    const int wr = wid >> 1, wc = wid & 1;
    const int m0 = blockIdx.y * BM, n0 = blockIdx.x * 128;
    const int srow0 = wid * 16 + (lane >> 2), schunk = lane & 3;
    const int ar = tid >> 3, ac = (tid & 7) * 4;
    const int lrow = lane & 15, koff = lane >> 4;
    f32x4 acc[4][4] = {};
    for (int kt = 0; kt < KT; ++kt) {
        const int k0 = kt * BK;
        #pragma unroll
        for (int s = 0; s < 2; ++s) {
            const int row = srow0 + s * 64;
            const int kc = schunk ^ ((row >> 1) & 3);
            const bf16_t* gsrc = W + (size_t)(n0 + row) * K + k0 + kc * 8;
            bf16_t* ldsbase = &Bs[wid * 16 + s * 64][0];
            __builtin_amdgcn_global_load_lds(
                (const __attribute__((address_space(1))) void*)gsrc,
                (__attribute__((address_space(3))) void*)ldsbase, 16, 0, 0);
        }
        #pragma unroll
        for (int p = 0; p < 4; ++p) {
            const int row = p * 32 + ar;
            const int gr = m0 + row;
            f32x4 v = {};
            if (gr < M) v = *(const f32x4*)(X + (size_t)gr * LD + k0 + ac);
            bf16x4 h;
            h[0] = (bf16_t)v[0]; h[1] = (bf16_t)v[1];
            h[2] = (bf16_t)v[2]; h[3] = (bf16_t)v[3];
            *(bf16x4*)(&As[row][ac]) = h;
        }
        __syncthreads();
        bf16x8 a[4], bb[4];
        #pragma unroll
        for (int i = 0; i < 4; ++i) {
            a[i] = *(const bf16x8*)(&As[wr * 64 + i * 16 + lrow][koff * 8]);
            const int col = wc * 64 + i * 16 + lrow;
            const int kc = koff ^ ((col >> 1) & 3);
            bb[i] = *(const bf16x8*)(&Bs[col][kc * 8]);
        }
        #pragma unroll
        for (int i = 0; i < 4; ++i)
            #pragma unroll
            for (int j = 0; j < 4; ++j)
                acc[i][j] = __builtin_amdgcn_mfma_f32_16x16x32_bf16(a[i], bb[j], acc[i][j], 0, 0, 0);
        __syncthreads();
    }
    #pragma unroll
    for (int j = 0; j < 4; ++j) {
        const int col = n0 + wc * 64 + j * 16 + lrow;
        float bv = 0.f;
        if constexpr (BIAS) bv = bias[col];
        #pragma unroll
        for (int i = 0; i < 4; ++i) {
            const int rbase = m0 + wr * 64 + i * 16 + koff * 4;
            #pragma unroll
            for (int r = 0; r < 4; ++r) {
                const int gr = rbase + r;
                if (gr < M) Y[(size_t)gr * LD + col] = acc[i][j][r] + bv;
            }
        }
    }
}

// ---------------- launch ----------------

extern "C" void kernel_launch(void* const* d_in, const int* in_sizes, int n_in,
                              void* d_out, int out_size, void* d_ws, size_t ws_size,
                              hipStream_t stream) {
    const float* x  = (const float*)d_in[0];
    const float* W0 = (const float*)d_in[1];
    const float* b0 = (const float*)d_in[2];
    const float* W1 = (const float*)d_in[3];
    const float* W2 = (const float*)d_in[4];
    float* out = (float*)d_out;

    const int E = in_sizes[0] / LD;  // 50000

    constexpr size_t W0P = (size_t)1024 * 896;
    constexpr size_t W1S = (size_t)1536 * 1536;
    constexpr size_t W2S = (size_t)1280 * 1280;
    bf16_t* wc0 = (bf16_t*)d_ws;
    bf16_t* wc1 = wc0 + W0P;
    bf16_t* wc2 = wc1 + W1S;
    bf16_t* xb  = wc2 + W2S;

    const size_t need = (W0P + W1S + W2S + (size_t)E * LD) * sizeof(bf16_t);
    const bool fast = ws_size >= need;

    cvt_w0_pad_kernel<<<(int)((W0P + 255) / 256), 256, 0, stream>>>(W0, wc0, 896, 896, (int)W0P);
    combine_wm_kernel<<<(int)(W1S / 256), 256, 0, stream>>>(W1, wc1, 768, 768, (int)W1S);
    combine_wm_kernel<<<(int)(W2S / 256), 256, 0, stream>>>(W2, wc2, 640, 640, (int)W2S);

    if (fast) {
        const long n8 = (long)E * LD / 8;
        cvt_x_kernel<<<4096, 256, 0, stream>>>(x, xb, n8);
        const int mt = (E + 255) / 256;
        gemm256_kernel<1024, 896, 896, true>
            <<<dim3(4, mt), 512, 0, stream>>>(xb, wc0, b0, out, E);
        gemm256_kernel<1536, 1536, 1536, false>
            <<<dim3(6, mt), 512, 0, stream>>>(xb + 896, wc1, nullptr, out + 896, E);
        gemm256_kernel<1280, 1280, 1280, false>
            <<<dim3(5, mt), 512, 0, stream>>>(xb + 2432, wc2, nullptr, out + 2432, E);
    } else {
        const int mt = (E + 127) / 128;
        gemm_fb_kernel<896, 896, true>
            <<<dim3(896 / 128, mt), 256, 0, stream>>>(x, wc0, b0, out, E);  // note: wc0 padded rows unused (N=896 grid)
        gemm_fb_kernel<1536, 1536, false>
            <<<dim3(1536 / 128, mt), 256, 0, stream>>>(x + 896, wc1, nullptr, out + 896, E);
        gemm_fb_kernel<1280, 1280, false>
            <<<dim3(1280 / 128, mt), 256, 0, stream>>>(x + 2432, wc2, nullptr, out + 2432, E);
    }
}